// Round 1
// baseline (19850.995 us; speedup 1.0000x reference)
//
#include <hip/hip_runtime.h>
#include <hip/hip_fp16.h>

#define B_ 64
#define T_ 1024
#define IN_ 512
#define H_ 512
#define G_ 1536

// ---------------------------------------------------------------------------
// w_hh fp32 -> fp16 (ws). 50,331,648 elements, 4 per thread.
// ---------------------------------------------------------------------------
__global__ __launch_bounds__(256) void convert_whh(const float* __restrict__ w,
                                                   __half* __restrict__ w16) {
  size_t i = ((size_t)blockIdx.x * blockDim.x + threadIdx.x) * 4;
  float4 v = *reinterpret_cast<const float4*>(w + i);
  __half2 p0 = __floats2half2_rn(v.x, v.y);
  __half2 p1 = __floats2half2_rn(v.z, v.w);
  *reinterpret_cast<__half2*>(w16 + i) = p0;
  *reinterpret_cast<__half2*>(w16 + i + 2) = p1;
}

// ---------------------------------------------------------------------------
// ih_all[b,t,g] = sum_i xs[b,t,i] * w_ih[b,i,g] + b_ih[b,g], stored fp16.
// fp32 VALU tiled GEMM: 64x64 tile, K-chunk 16, 256 threads, 4x4 per thread.
// ---------------------------------------------------------------------------
__global__ __launch_bounds__(256) void gemm_ih(const float* __restrict__ xs,
                                               const float* __restrict__ w_ih,
                                               const float* __restrict__ b_ih,
                                               __half* __restrict__ ih16) {
  int b  = blockIdx.z;
  int n0 = blockIdx.x * 64;
  int m0 = blockIdx.y * 64;
  const float* A  = xs   + (size_t)b * T_ * IN_;   // [1024][512]
  const float* Bw = w_ih + (size_t)b * IN_ * G_;   // [512][1536]

  __shared__ float As[16][68];   // [k][m], padded stride 68 (16B-aligned rows, no 4-way conflicts)
  __shared__ float Bs[16][64];   // [k][n]

  int tid = threadIdx.x;
  int tx = tid & 15, ty = tid >> 4;          // 16x16 threads, each owns 4x4
  int lam = tid >> 2;                        // A-load row 0..63
  int lak = (tid & 3) * 4;                   // A-load k 0,4,8,12
  int lbk = tid >> 4;                        // B-load k 0..15
  int lbn = (tid & 15) * 4;                  // B-load n

  float acc[4][4] = {};

  for (int k0 = 0; k0 < IN_; k0 += 16) {
    float4 av = *reinterpret_cast<const float4*>(A  + (size_t)(m0 + lam) * IN_ + k0 + lak);
    float4 bv = *reinterpret_cast<const float4*>(Bw + (size_t)(k0 + lbk) * G_ + n0 + lbn);
    As[lak + 0][lam] = av.x;
    As[lak + 1][lam] = av.y;
    As[lak + 2][lam] = av.z;
    As[lak + 3][lam] = av.w;
    *reinterpret_cast<float4*>(&Bs[lbk][lbn]) = bv;
    __syncthreads();
#pragma unroll
    for (int kk = 0; kk < 16; ++kk) {
      float4 aq = *reinterpret_cast<const float4*>(&As[kk][ty * 4]);
      float4 bq = *reinterpret_cast<const float4*>(&Bs[kk][tx * 4]);
      float a[4] = {aq.x, aq.y, aq.z, aq.w};
      float bb[4] = {bq.x, bq.y, bq.z, bq.w};
#pragma unroll
      for (int i = 0; i < 4; ++i)
#pragma unroll
        for (int j = 0; j < 4; ++j) acc[i][j] += a[i] * bb[j];
    }
    __syncthreads();
  }

  float4 bias = *reinterpret_cast<const float4*>(b_ih + (size_t)b * G_ + n0 + tx * 4);
#pragma unroll
  for (int i = 0; i < 4; ++i) {
    size_t row = (size_t)b * T_ + m0 + ty * 4 + i;
    __half2* dst = reinterpret_cast<__half2*>(ih16 + row * G_ + n0 + tx * 4);
    dst[0] = __floats2half2_rn(acc[i][0] + bias.x, acc[i][1] + bias.y);
    dst[1] = __floats2half2_rn(acc[i][2] + bias.z, acc[i][3] + bias.w);
  }
}

// ---------------------------------------------------------------------------
// One recurrence step. grid (8, 64): blockIdx.y = batch, blockIdx.x = group of
// 64 h-indices. 768 threads: 4-way K-split x (3 gates x 64 lanes).
// hh = h_prev @ w_hh + b_hh, then gates, write hy into outputs[b][t][:].
// h state IS the outputs buffer (step t reads outputs[b][t-1]) -> kernel
// boundary provides the grid sync.
// ---------------------------------------------------------------------------
__global__ __launch_bounds__(768) void gru_step(const __half* __restrict__ w16,  // [b][k][g]
                                                const float* __restrict__ b_hh,  // [b][g]
                                                const __half* __restrict__ ih16, // [b][t][g]
                                                const float* __restrict__ hprev_base,
                                                long long hprev_bstride,
                                                float* __restrict__ out, int t) {
  __shared__ float hsh[512];
  __shared__ float psh[768];

  int b   = blockIdx.y;
  int grp = blockIdx.x;   // 0..7
  int tid = threadIdx.x;  // 0..767

  const float* hp = hprev_base + (size_t)b * hprev_bstride;
  if (tid < 512) hsh[tid] = hp[tid];
  __syncthreads();

  int kq   = tid / 192;   // 0..3 K-split
  int r    = tid % 192;
  int type = r / 64;      // 0=r gate, 1=i gate, 2=n gate
  int lane = r % 64;
  int g    = type * 512 + grp * 64 + lane;

  const __half* wcol = w16 + ((size_t)b * 512 + (size_t)kq * 128) * G_ + g;
  float acc = 0.f;
#pragma unroll 8
  for (int k = 0; k < 128; ++k)
    acc += hsh[kq * 128 + k] * __half2float(wcol[(size_t)k * G_]);
  psh[tid] = acc;
  __syncthreads();

  if (tid < 192) {
    float hh = psh[tid] + psh[tid + 192] + psh[tid + 384] + psh[tid + 576] +
               b_hh[(size_t)b * G_ + g];
    psh[tid] = hh;
  }
  __syncthreads();

  if (tid < 64) {
    int j = grp * 64 + tid;
    size_t ihoff = ((size_t)b * T_ + t) * G_ + j;
    float i_r = __half2float(ih16[ihoff]);
    float i_i = __half2float(ih16[ihoff + 512]);
    float i_n = __half2float(ih16[ihoff + 1024]);
    float h_r = psh[tid], h_i = psh[tid + 64], h_n = psh[tid + 128];
    float rg = 1.f / (1.f + __expf(-(i_r + h_r)));
    float ig = 1.f / (1.f + __expf(-(i_i + h_i)));
    float ng = tanhf(i_n + rg * h_n);
    float h  = hsh[j];
    float hy = ng + ig * (h - ng);
    out[((size_t)b * T_ + (size_t)t) * H_ + j] = hy;
  }
}

// ---------------------------------------------------------------------------
// final_state[b][j] = outputs[b][T-1][j]
// ---------------------------------------------------------------------------
__global__ __launch_bounds__(256) void final_copy(const float* __restrict__ out,
                                                  float* __restrict__ fin) {
  int i = blockIdx.x * 256 + threadIdx.x;  // 0..32767
  int b = i >> 9, j = i & 511;
  fin[i] = out[((size_t)b * T_ + (T_ - 1)) * H_ + j];
}

extern "C" void kernel_launch(void* const* d_in, const int* in_sizes, int n_in,
                              void* d_out, int out_size, void* d_ws, size_t ws_size,
                              hipStream_t stream) {
  const float* xs    = (const float*)d_in[0];
  const float* state = (const float*)d_in[1];
  const float* w_ih  = (const float*)d_in[2];
  const float* w_hh  = (const float*)d_in[3];
  const float* b_ih  = (const float*)d_in[4];
  const float* b_hh  = (const float*)d_in[5];
  float* out = (float*)d_out;
  float* fin = out + (size_t)B_ * T_ * H_;

  // ws layout: [0, 96 MiB) w_hh fp16 ; [96 MiB, 288 MiB) ih_all fp16
  __half* w16  = (__half*)d_ws;
  __half* ih16 = w16 + (size_t)B_ * H_ * G_;

  convert_whh<<<(B_ * H_ * G_) / 4 / 256, 256, 0, stream>>>(w_hh, w16);

  dim3 ggrid(G_ / 64, T_ / 64, B_);
  gemm_ih<<<ggrid, 256, 0, stream>>>(xs, w_ih, b_ih, ih16);

  for (int t = 0; t < T_; ++t) {
    const float* hprev = (t == 0) ? state : out + (size_t)(t - 1) * H_;
    long long hstride  = (t == 0) ? (long long)H_ : (long long)T_ * H_;
    gru_step<<<dim3(8, B_), 768, 0, stream>>>(w16, b_hh, ih16, hprev, hstride, out, t);
  }

  final_copy<<<128, 256, 0, stream>>>(out, fin);
}

// Round 2
// 19073.531 us; speedup vs baseline: 1.0408x; 1.0408x over previous
//
#include <hip/hip_runtime.h>
#include <hip/hip_fp16.h>

#define B_ 64
#define T_ 1024
#define IN_ 512
#define H_ 512
#define G_ 1536

typedef _Float16 h2v __attribute__((ext_vector_type(2)));
typedef _Float16 h8v __attribute__((ext_vector_type(8)));

// ---------------------------------------------------------------------------
// Repack w_hh fp32 [b][k][g] -> fp16 k-pair-interleaved wp[b][kp][2g+e],
// kp = k/2, e = k%2. So {w[2kp][g], w[2kp+1][g]} sit adjacent -> one half2
// feeds v_dot2_f32_f16 directly.
// ---------------------------------------------------------------------------
__global__ __launch_bounds__(256) void convert_whh(const float* __restrict__ w,
                                                   __half* __restrict__ wp) {
  size_t i = (size_t)blockIdx.x * 256 + threadIdx.x;  // 6,291,456 threads
  int c  = (int)(i % 384);           // g-quad index (4 g's each)
  int kp = (int)((i / 384) % 256);
  int b  = (int)(i / (384 * 256));
  const float* r0 = w + ((size_t)b * 512 + 2 * kp) * G_ + c * 4;
  const float* r1 = r0 + G_;
  float4 a = *reinterpret_cast<const float4*>(r0);
  float4 d = *reinterpret_cast<const float4*>(r1);
  __half2* dst = reinterpret_cast<__half2*>(wp + ((size_t)b * 256 + kp) * 3072 + c * 8);
  dst[0] = __floats2half2_rn(a.x, d.x);
  dst[1] = __floats2half2_rn(a.y, d.y);
  dst[2] = __floats2half2_rn(a.z, d.z);
  dst[3] = __floats2half2_rn(a.w, d.w);
}

// ---------------------------------------------------------------------------
// ih_all[b,t,g] = sum_i xs[b,t,i] * w_ih[b,i,g] + b_ih[b,g], stored fp16.
// (unchanged from R1 — fp32 VALU tiled GEMM; MFMA conversion is next round)
// ---------------------------------------------------------------------------
__global__ __launch_bounds__(256) void gemm_ih(const float* __restrict__ xs,
                                               const float* __restrict__ w_ih,
                                               const float* __restrict__ b_ih,
                                               __half* __restrict__ ih16) {
  int b  = blockIdx.z;
  int n0 = blockIdx.x * 64;
  int m0 = blockIdx.y * 64;
  const float* A  = xs   + (size_t)b * T_ * IN_;
  const float* Bw = w_ih + (size_t)b * IN_ * G_;

  __shared__ float As[16][68];
  __shared__ float Bs[16][64];

  int tid = threadIdx.x;
  int tx = tid & 15, ty = tid >> 4;
  int lam = tid >> 2;
  int lak = (tid & 3) * 4;
  int lbk = tid >> 4;
  int lbn = (tid & 15) * 4;

  float acc[4][4] = {};

  for (int k0 = 0; k0 < IN_; k0 += 16) {
    float4 av = *reinterpret_cast<const float4*>(A  + (size_t)(m0 + lam) * IN_ + k0 + lak);
    float4 bv = *reinterpret_cast<const float4*>(Bw + (size_t)(k0 + lbk) * G_ + n0 + lbn);
    As[lak + 0][lam] = av.x;
    As[lak + 1][lam] = av.y;
    As[lak + 2][lam] = av.z;
    As[lak + 3][lam] = av.w;
    *reinterpret_cast<float4*>(&Bs[lbk][lbn]) = bv;
    __syncthreads();
#pragma unroll
    for (int kk = 0; kk < 16; ++kk) {
      float4 aq = *reinterpret_cast<const float4*>(&As[kk][ty * 4]);
      float4 bq = *reinterpret_cast<const float4*>(&Bs[kk][tx * 4]);
      float a[4] = {aq.x, aq.y, aq.z, aq.w};
      float bb[4] = {bq.x, bq.y, bq.z, bq.w};
#pragma unroll
      for (int i = 0; i < 4; ++i)
#pragma unroll
        for (int j = 0; j < 4; ++j) acc[i][j] += a[i] * bb[j];
    }
    __syncthreads();
  }

  float4 bias = *reinterpret_cast<const float4*>(b_ih + (size_t)b * G_ + n0 + tx * 4);
#pragma unroll
  for (int i = 0; i < 4; ++i) {
    size_t row = (size_t)b * T_ + m0 + ty * 4 + i;
    __half2* dst = reinterpret_cast<__half2*>(ih16 + row * G_ + n0 + tx * 4);
    dst[0] = __floats2half2_rn(acc[i][0] + bias.x, acc[i][1] + bias.y);
    dst[1] = __floats2half2_rn(acc[i][2] + bias.z, acc[i][3] + bias.w);
  }
}

// ---------------------------------------------------------------------------
// One recurrence step. grid (8, 64): blockIdx.y = batch, blockIdx.x = 64-wide
// j-group. 384 threads = 8-way K-split x 48 g-quad chunks (192 g = 3 gates x
// 64 j). Each thread: 32 iters of {16B wp load, h2 LDS broadcast, 4 dot2}.
// ---------------------------------------------------------------------------
__global__ __launch_bounds__(384) void gru_step(const __half* __restrict__ wp,   // [b][256][3072]
                                                const float* __restrict__ b_hh,  // [b][g]
                                                const __half* __restrict__ ih16, // [b][t][g]
                                                const float* __restrict__ hprev_base,
                                                long long hprev_bstride,
                                                float* __restrict__ out, int t) {
  __shared__ h2v  hsh2[256];                 // h as fp16 k-pairs
  __shared__ float hsh[512];                 // h fp32 for the hy formula
  __shared__ __align__(16) float part[8][192];
  __shared__ float gsh[192];

  int b   = blockIdx.y;
  int grp = blockIdx.x;   // 0..7 -> j0 = grp*64
  int tid = threadIdx.x;  // 0..383

  const float* hp = hprev_base + (size_t)b * hprev_bstride;
  if (tid < 256) {
    float2 hv = *reinterpret_cast<const float2*>(hp + tid * 2);
    h2v h2; h2[0] = (_Float16)hv.x; h2[1] = (_Float16)hv.y;
    hsh2[tid] = h2;
    hsh[2 * tid]     = hv.x;
    hsh[2 * tid + 1] = hv.y;
  }
  __syncthreads();

  int kq   = tid / 48;        // 0..7  (K-split: kp range [kq*32, kq*32+32))
  int c    = tid % 48;        // 0..47 g-quad chunk
  int type = c / 16;          // gate
  int jl4  = (c % 16) * 4;
  int j0   = grp * 64;
  int g    = type * 512 + j0 + jl4;   // 4 consecutive g's

  const h8v* wrow = reinterpret_cast<const h8v*>(
      wp + ((size_t)b * 256 + (size_t)kq * 32) * 3072 + 2 * g);
  // kp-row stride in h8v units: 3072/8 = 384

  float a0 = 0.f, a1 = 0.f, a2 = 0.f, a3 = 0.f;
#pragma unroll 8
  for (int i = 0; i < 32; ++i) {
    h8v w8 = wrow[(size_t)i * 384];
    h2v hk = hsh2[kq * 32 + i];
    a0 = __builtin_amdgcn_fdot2(__builtin_shufflevector(w8, w8, 0, 1), hk, a0, false);
    a1 = __builtin_amdgcn_fdot2(__builtin_shufflevector(w8, w8, 2, 3), hk, a1, false);
    a2 = __builtin_amdgcn_fdot2(__builtin_shufflevector(w8, w8, 4, 5), hk, a2, false);
    a3 = __builtin_amdgcn_fdot2(__builtin_shufflevector(w8, w8, 6, 7), hk, a3, false);
  }
  float4 pv = {a0, a1, a2, a3};
  *reinterpret_cast<float4*>(&part[kq][c * 4]) = pv;
  __syncthreads();

  if (tid < 192) {
    // partial index p = c*4 + e maps to type*64 + jl == tid
    float s = 0.f;
#pragma unroll
    for (int q = 0; q < 8; ++q) s += part[q][tid];
    int gg = (tid / 64) * 512 + j0 + (tid % 64);
    gsh[tid] = s + b_hh[(size_t)b * G_ + gg];
  }
  __syncthreads();

  if (tid < 64) {
    int j = j0 + tid;
    size_t ihoff = ((size_t)b * T_ + t) * G_ + j;
    float i_r = __half2float(ih16[ihoff]);
    float i_i = __half2float(ih16[ihoff + 512]);
    float i_n = __half2float(ih16[ihoff + 1024]);
    float h_r = gsh[tid], h_i = gsh[64 + tid], h_n = gsh[128 + tid];
    float rg = 1.f / (1.f + __expf(-(i_r + h_r)));
    float ig = 1.f / (1.f + __expf(-(i_i + h_i)));
    float ng = tanhf(i_n + rg * h_n);
    float h  = hsh[j];
    float hy = ng + ig * (h - ng);
    out[((size_t)b * T_ + (size_t)t) * H_ + j] = hy;
  }
}

// ---------------------------------------------------------------------------
// final_state[b][j] = outputs[b][T-1][j]
// ---------------------------------------------------------------------------
__global__ __launch_bounds__(256) void final_copy(const float* __restrict__ out,
                                                  float* __restrict__ fin) {
  int i = blockIdx.x * 256 + threadIdx.x;
  fin[i] = out[((size_t)(i >> 9) * T_ + (T_ - 1)) * H_ + (i & 511)];
}

extern "C" void kernel_launch(void* const* d_in, const int* in_sizes, int n_in,
                              void* d_out, int out_size, void* d_ws, size_t ws_size,
                              hipStream_t stream) {
  const float* xs    = (const float*)d_in[0];
  const float* state = (const float*)d_in[1];
  const float* w_ih  = (const float*)d_in[2];
  const float* w_hh  = (const float*)d_in[3];
  const float* b_ih  = (const float*)d_in[4];
  const float* b_hh  = (const float*)d_in[5];
  float* out = (float*)d_out;
  float* fin = out + (size_t)B_ * T_ * H_;

  __half* wp   = (__half*)d_ws;                       // 96 MiB packed fp16 w_hh
  __half* ih16 = wp + (size_t)B_ * H_ * G_;           // 192 MiB fp16 ih_all

  convert_whh<<<(B_ * 256 * 384) / 256, 256, 0, stream>>>(w_hh, wp);

  dim3 ggrid(G_ / 64, T_ / 64, B_);
  gemm_ih<<<ggrid, 256, 0, stream>>>(xs, w_ih, b_ih, ih16);

  for (int t = 0; t < T_; ++t) {
    const float* hprev = (t == 0) ? state : out + (size_t)(t - 1) * H_;
    long long hstride  = (t == 0) ? (long long)H_ : (long long)T_ * H_;
    gru_step<<<dim3(8, B_), 384, 0, stream>>>(wp, b_hh, ih16, hprev, hstride, out, t);
  }

  final_copy<<<128, 256, 0, stream>>>(out, fin);
}